// Round 20
// baseline (109.422 us; speedup 1.0000x reference)
//
#include <hip/hip_runtime.h>
#include <hip/hip_bf16.h>

// SpiralDeblock: B=8, N_IN=7056, N_UP=28224, SEQ=9, CIN=64, COUT=32
namespace {
constexpr int kB    = 8;
constexpr int kNIn  = 7056;
constexpr int kNUp  = 28224;
constexpr int kSeq  = 9;
constexpr int kCin  = 64;
constexpr int kCout = 32;
constexpr int kE    = 3 * kNUp;          // 84672
constexpr int kMRows = kB * kNUp;        // 225792
constexpr int kMTiles = kMRows / 16;     // 14112
constexpr int kTilesPerB = kNUp / 16;    // 1764
constexpr int kWFragN = 18 * 2 * 64 * 8; // 18432 bf16 values (36,864 B)
constexpr int kCap   = 24;               // bucket capacity
constexpr int kGemmGrid = 1768;          // 8 tiles/block; 1768 = 8*221 (swizzle-exact)

// ws layout (bytes), 16B-aligned. poolb: [b][r][c] (batch-sliced -> per-XCD L2
// residency; r18 proved transposing costs 8 us).
constexpr size_t kOffPool   = 0;                          // 28,901,376
constexpr size_t kOffWfrag  = 28901376;                   // 36,864
constexpr size_t kOffCur    = kOffWfrag + 36864;          // 112,896
constexpr size_t kOffBucket = kOffCur + 112896;           // N_UP*24*8 = 5,419,008
}

typedef __attribute__((ext_vector_type(8))) short short8;
typedef __attribute__((ext_vector_type(4))) float f32x4;

__device__ __forceinline__ unsigned short f32_to_bf16(float f) {  // RNE
    unsigned int u = __float_as_uint(f);
    u += 0x7fffu + ((u >> 16) & 1u);
    return (unsigned short)(u >> 16);
}

// --- zero cursor (graph-safe) ----------------------------------------------
__global__ __launch_bounds__(256) void zero_kernel(int* __restrict__ cursor) {
    int i = blockIdx.x * 256 + threadIdx.x;
    if (i < kNUp) cursor[i] = 0;
}

// --- merged prep: blocks [0,72) W->fragment transpose; rest bucket edges ----
__global__ __launch_bounds__(256) void prep_kernel(const float* __restrict__ W,
                                                   unsigned short* __restrict__ wfrag,
                                                   const int* __restrict__ row,
                                                   const int* __restrict__ col,
                                                   const float* __restrict__ val,
                                                   int* __restrict__ cursor,
                                                   uint2* __restrict__ bucket) {
    int bid = blockIdx.x;
    if (bid < kWFragN / 256) {
        int i  = bid * 256 + threadIdx.x;
        int j  = i & 7;
        int l  = (i >> 3) & 63;
        int ct = (i >> 9) & 1;
        int ks = i >> 10;                            // 0..17
        int k  = ks * 32 + (l >> 4) * 8 + j;
        int o  = ct * 16 + (l & 15);
        wfrag[i] = f32_to_bf16(W[k * kCout + o]);
    } else {
        int e = (bid - kWFragN / 256) * 256 + threadIdx.x;
        if (e >= kE) return;
        int r = row[e];
        int slot = atomicAdd(&cursor[r], 1);
        if ((unsigned)slot < (unsigned)kCap)
            bucket[(size_t)r * kCap + slot] = make_uint2((unsigned)col[e], __float_as_uint(val[e]));
    }
}

// --- pooled[b,r,c] = sum_{edges of r} x[b,col,c]*val, stored bf16 -----------
// b = blockIdx&7: batch<->XCD affinity (1.8 MB x-slice per XCD L2). 22.2 us (r10).
// NEW: x reads are nontemporal (scattered, zero L1 reuse -> skip L1 alloc).
__global__ __launch_bounds__(256) void pool_gather(const float* __restrict__ x,
                                                   const int* __restrict__ cursor,
                                                   const uint2* __restrict__ bucket,
                                                   unsigned short* __restrict__ poolb) {
    int t  = threadIdx.x;
    int c4 = t & 15;
    int b  = blockIdx.x & 7;
    int rb = blockIdx.x >> 3;
    int r  = rb * 16 + (t >> 4);
    int n  = min(cursor[r], kCap);
    const uint2* bk = bucket + (size_t)r * kCap;
    const float* xb = x + (size_t)b * kNIn * kCin + (size_t)c4 * 4;

    f32x4 acc = {0.f, 0.f, 0.f, 0.f};
#pragma unroll
    for (int p = 0; p < 4; ++p) {
        if (2 * p < n) {
            uint4 q = *reinterpret_cast<const uint4*>(bk + 2 * p);
            unsigned c0 = min(q.x, (unsigned)(kNIn - 1));
            float    v0 = __uint_as_float(q.y);
            unsigned c1 = min(q.z, (unsigned)(kNIn - 1));
            float    v1 = (2 * p + 1 < n) ? __uint_as_float(q.w) : 0.f;
            f32x4 xv0 = __builtin_nontemporal_load(
                reinterpret_cast<const f32x4*>(xb + (size_t)c0 * kCin));
            f32x4 xv1 = __builtin_nontemporal_load(
                reinterpret_cast<const f32x4*>(xb + (size_t)c1 * kCin));
#pragma unroll
            for (int j = 0; j < 4; ++j)
                acc[j] = fmaf(xv1[j], v1, fmaf(xv0[j], v0, acc[j]));
        }
    }
    for (int k = 8; k < n; ++k) {                    // rare tail
        uint2 ev = bk[k];
        float v = __uint_as_float(ev.y);
        f32x4 xv = __builtin_nontemporal_load(
            reinterpret_cast<const f32x4*>(xb + (size_t)ev.x * kCin));
#pragma unroll
        for (int j = 0; j < 4; ++j) acc[j] = fmaf(xv[j], v, acc[j]);
    }
    ushort4 o;
    o.x = f32_to_bf16(acc[0]);
    o.y = f32_to_bf16(acc[1]);
    o.z = f32_to_bf16(acc[2]);
    o.w = f32_to_bf16(acc[3]);
    *reinterpret_cast<ushort4*>(poolb + ((size_t)b * kNUp + r) * kCin + c4 * 4) = o;
}

// --- MFMA GEMM (r17 config) + NT loads on the A-gather ----------------------
// Reconciled model: A-gather = 4.06M scattered 64B line-fills; measured 34 us
// = ~5.1 cyc/fill/CU = L1 miss-handling throughput (explains why ILP/MLP/
// occupancy/coalescing were all null -- they only queue more misses into a
// fixed-rate fill pipe). nt loads skip L1 allocation for these zero-reuse
// streams. Out-stores stay NT (r19).
__global__ __launch_bounds__(512, 8) void gemm_mfma(const unsigned short* __restrict__ poolb,
                                                    const unsigned short* __restrict__ wfrag,
                                                    const float* __restrict__ bias,
                                                    const int* __restrict__ indices,
                                                    float* __restrict__ out) {
    __shared__ short8 Bs[18 * 2 * 64];               // 2304 short8 = 36,864 B
    int t = threadIdx.x;
    const short8* wf = (const short8*)wfrag;
#pragma unroll
    for (int i = 0; i < 5; ++i) {                    // 2304 = 4*512 + 256
        int idx = i * 512 + t;
        if (idx < 18 * 2 * 64) Bs[idx] = wf[idx];
    }

    int l = t & 63;
    int w = t >> 6;                                  // wave 0..7
    int m  = l & 15;
    int kg = l >> 4;
    int bid = blockIdx.x;
    int wgid = (bid & 7) * 221 + (bid >> 3);         // grid 1768 = 8*221
    int mtile = wgid * 8 + w;
    bool active = (mtile < kMTiles);                 // wave-uniform guard
    if (active) {
        int b  = mtile / kTilesPerB;
        int nn = (mtile - b * kTilesPerB) * 16 + m;
        const unsigned short* pb = poolb + (size_t)b * kNUp * kCin;

        int idxs[kSeq];
#pragma unroll
        for (int s = 0; s < kSeq; ++s) idxs[s] = indices[nn * kSeq + s];

        float bs0 = bias[m];
        float bs1 = bias[16 + m];

        __syncthreads();                             // Bs ready

        f32x4 acc0 = {0.f, 0.f, 0.f, 0.f};
        f32x4 acc1 = {0.f, 0.f, 0.f, 0.f};
#pragma unroll
        for (int s = 0; s < kSeq; ++s) {
            const short8* ar = (const short8*)(pb + (size_t)idxs[s] * kCin);
            short8 a0 = __builtin_nontemporal_load(&ar[kg]);      // ch 0..31
            short8 a1 = __builtin_nontemporal_load(&ar[4 + kg]);  // ch 32..63
            short8 b00 = Bs[(4 * s + 0) * 64 + l];
            short8 b01 = Bs[(4 * s + 1) * 64 + l];
            short8 b10 = Bs[(4 * s + 2) * 64 + l];
            short8 b11 = Bs[(4 * s + 3) * 64 + l];
            acc0 = __builtin_amdgcn_mfma_f32_16x16x32_bf16(a0, b00, acc0, 0, 0, 0);
            acc1 = __builtin_amdgcn_mfma_f32_16x16x32_bf16(a0, b01, acc1, 0, 0, 0);
            acc0 = __builtin_amdgcn_mfma_f32_16x16x32_bf16(a1, b10, acc0, 0, 0, 0);
            acc1 = __builtin_amdgcn_mfma_f32_16x16x32_bf16(a1, b11, acc1, 0, 0, 0);
        }

        int orow0 = mtile * 16 + kg * 4;
#pragma unroll
        for (int r = 0; r < 4; ++r) {
            size_t orow = (size_t)(orow0 + r) * kCout;
            __builtin_nontemporal_store(fmaxf(acc0[r] + bs0, 0.f), &out[orow + m]);
            __builtin_nontemporal_store(fmaxf(acc1[r] + bs1, 0.f), &out[orow + 16 + m]);
        }
    } else {
        __syncthreads();                             // keep barrier uniform
    }
}

extern "C" void kernel_launch(void* const* d_in, const int* in_sizes, int n_in,
                              void* d_out, int out_size, void* d_ws, size_t ws_size,
                              hipStream_t stream) {
    const float* x    = (const float*)d_in[0];
    const float* val  = (const float*)d_in[1];
    const float* W    = (const float*)d_in[2];
    const float* bias = (const float*)d_in[3];
    const int* row     = (const int*)d_in[4];
    const int* col     = (const int*)d_in[5];
    const int* indices = (const int*)d_in[6];
    float* out = (float*)d_out;

    char* wsb = (char*)d_ws;
    unsigned short* poolb = (unsigned short*)(wsb + kOffPool);
    unsigned short* wfrag = (unsigned short*)(wsb + kOffWfrag);
    int* cursor  = (int*)(wsb + kOffCur);
    uint2* bucket = (uint2*)(wsb + kOffBucket);

    zero_kernel<<<(kNUp + 255) / 256, 256, 0, stream>>>(cursor);

    constexpr int prep_blocks = kWFragN / 256 + (kE + 255) / 256;  // 72 + 331
    prep_kernel<<<prep_blocks, 256, 0, stream>>>(W, wfrag, row, col, val, cursor, bucket);

    pool_gather<<<kNUp / 16 * kB, 256, 0, stream>>>(x, cursor, bucket, poolb);

    gemm_mfma<<<kGemmGrid, 512, 0, stream>>>(poolb, wfrag, bias, indices, out);
}

// Round 21
// 74.132 us; speedup vs baseline: 1.4761x; 1.4761x over previous
//
#include <hip/hip_runtime.h>
#include <hip/hip_bf16.h>

// SpiralDeblock: B=8, N_IN=7056, N_UP=28224, SEQ=9, CIN=64, COUT=32
// FINAL CONFIG (r19, best verified 74.0 us). Ledger (all directly measured):
//   gemm 34 us  -- scattered-gather line-fill wall (7 levers probed, all null/neg)
//   pool 22 us  -- same wall on the x-gather side (XCD affinity won +5.6)
//   fixed ~18 us -- zero+prep+4 graph nodes (coop grid.sync costs 90us/sync -> dead end)
namespace {
constexpr int kB    = 8;
constexpr int kNIn  = 7056;
constexpr int kNUp  = 28224;
constexpr int kSeq  = 9;
constexpr int kCin  = 64;
constexpr int kCout = 32;
constexpr int kE    = 3 * kNUp;          // 84672
constexpr int kMRows = kB * kNUp;        // 225792
constexpr int kMTiles = kMRows / 16;     // 14112
constexpr int kTilesPerB = kNUp / 16;    // 1764
constexpr int kWFragN = 18 * 2 * 64 * 8; // 18432 bf16 values (36,864 B)
constexpr int kCap   = 24;               // bucket capacity
constexpr int kGemmGrid = 1768;          // 8 tiles/block; 1768 = 8*221 (swizzle-exact)

// ws layout (bytes), 16B-aligned. poolb: [b][r][c] (batch-sliced -> per-XCD L2
// residency; r18 proved transposing costs 8 us, r20 proved nt-loads cost 18).
constexpr size_t kOffPool   = 0;                          // 28,901,376
constexpr size_t kOffWfrag  = 28901376;                   // 36,864
constexpr size_t kOffCur    = kOffWfrag + 36864;          // 112,896
constexpr size_t kOffBucket = kOffCur + 112896;           // N_UP*24*8 = 5,419,008
}

typedef __attribute__((ext_vector_type(8))) short short8;
typedef __attribute__((ext_vector_type(4))) float f32x4;

__device__ __forceinline__ unsigned short f32_to_bf16(float f) {  // RNE
    unsigned int u = __float_as_uint(f);
    u += 0x7fffu + ((u >> 16) & 1u);
    return (unsigned short)(u >> 16);
}

// --- zero cursor (graph-safe) ----------------------------------------------
__global__ __launch_bounds__(256) void zero_kernel(int* __restrict__ cursor) {
    int i = blockIdx.x * 256 + threadIdx.x;
    if (i < kNUp) cursor[i] = 0;
}

// --- merged prep: blocks [0,72) W->fragment transpose; rest bucket edges ----
__global__ __launch_bounds__(256) void prep_kernel(const float* __restrict__ W,
                                                   unsigned short* __restrict__ wfrag,
                                                   const int* __restrict__ row,
                                                   const int* __restrict__ col,
                                                   const float* __restrict__ val,
                                                   int* __restrict__ cursor,
                                                   uint2* __restrict__ bucket) {
    int bid = blockIdx.x;
    if (bid < kWFragN / 256) {
        int i  = bid * 256 + threadIdx.x;
        int j  = i & 7;
        int l  = (i >> 3) & 63;
        int ct = (i >> 9) & 1;
        int ks = i >> 10;                            // 0..17
        int k  = ks * 32 + (l >> 4) * 8 + j;
        int o  = ct * 16 + (l & 15);
        wfrag[i] = f32_to_bf16(W[k * kCout + o]);
    } else {
        int e = (bid - kWFragN / 256) * 256 + threadIdx.x;
        if (e >= kE) return;
        int r = row[e];
        int slot = atomicAdd(&cursor[r], 1);
        if ((unsigned)slot < (unsigned)kCap)
            bucket[(size_t)r * kCap + slot] = make_uint2((unsigned)col[e], __float_as_uint(val[e]));
    }
}

// --- pooled[b,r,c] = sum_{edges of r} x[b,col,c]*val, stored bf16 -----------
// b = blockIdx&7: batch<->XCD affinity (1.8 MB x-slice per XCD L2). 22.2 us (r10).
__global__ __launch_bounds__(256) void pool_gather(const float* __restrict__ x,
                                                   const int* __restrict__ cursor,
                                                   const uint2* __restrict__ bucket,
                                                   unsigned short* __restrict__ poolb) {
    int t  = threadIdx.x;
    int c4 = t & 15;
    int b  = blockIdx.x & 7;
    int rb = blockIdx.x >> 3;
    int r  = rb * 16 + (t >> 4);
    int n  = min(cursor[r], kCap);
    const uint2* bk = bucket + (size_t)r * kCap;
    const float* xb = x + (size_t)b * kNIn * kCin + (size_t)c4 * 4;

    f32x4 acc = {0.f, 0.f, 0.f, 0.f};
#pragma unroll
    for (int p = 0; p < 4; ++p) {
        if (2 * p < n) {
            uint4 q = *reinterpret_cast<const uint4*>(bk + 2 * p);
            unsigned c0 = min(q.x, (unsigned)(kNIn - 1));
            float    v0 = __uint_as_float(q.y);
            unsigned c1 = min(q.z, (unsigned)(kNIn - 1));
            float    v1 = (2 * p + 1 < n) ? __uint_as_float(q.w) : 0.f;
            f32x4 xv0 = *reinterpret_cast<const f32x4*>(xb + (size_t)c0 * kCin);
            f32x4 xv1 = *reinterpret_cast<const f32x4*>(xb + (size_t)c1 * kCin);
#pragma unroll
            for (int j = 0; j < 4; ++j)
                acc[j] = fmaf(xv1[j], v1, fmaf(xv0[j], v0, acc[j]));
        }
    }
    for (int k = 8; k < n; ++k) {                    // rare tail
        uint2 ev = bk[k];
        float v = __uint_as_float(ev.y);
        f32x4 xv = *reinterpret_cast<const f32x4*>(xb + (size_t)ev.x * kCin);
#pragma unroll
        for (int j = 0; j < 4; ++j) acc[j] = fmaf(xv[j], v, acc[j]);
    }
    ushort4 o;
    o.x = f32_to_bf16(acc[0]);
    o.y = f32_to_bf16(acc[1]);
    o.z = f32_to_bf16(acc[2]);
    o.w = f32_to_bf16(acc[3]);
    *reinterpret_cast<ushort4*>(poolb + ((size_t)b * kNUp + r) * kCin + c4 * 4) = o;
}

// --- MFMA GEMM (r17 config) + NT out-stores (r19) ---------------------------
// 8 waves/block, one 16-row tile per wave, shared 36.9KB Bs fill, 32 waves/CU.
// A-gather loads are PLAIN (cached): pooled slice is L2-resident per XCD;
// r20 proved nt-loads evict it (34 -> 52 us). Out-stores NT (write-once).
__global__ __launch_bounds__(512, 8) void gemm_mfma(const unsigned short* __restrict__ poolb,
                                                    const unsigned short* __restrict__ wfrag,
                                                    const float* __restrict__ bias,
                                                    const int* __restrict__ indices,
                                                    float* __restrict__ out) {
    __shared__ short8 Bs[18 * 2 * 64];               // 2304 short8 = 36,864 B
    int t = threadIdx.x;
    const short8* wf = (const short8*)wfrag;
#pragma unroll
    for (int i = 0; i < 5; ++i) {                    // 2304 = 4*512 + 256
        int idx = i * 512 + t;
        if (idx < 18 * 2 * 64) Bs[idx] = wf[idx];
    }

    int l = t & 63;
    int w = t >> 6;                                  // wave 0..7
    int m  = l & 15;
    int kg = l >> 4;
    int bid = blockIdx.x;
    int wgid = (bid & 7) * 221 + (bid >> 3);         // grid 1768 = 8*221
    int mtile = wgid * 8 + w;
    bool active = (mtile < kMTiles);                 // wave-uniform guard
    if (active) {
        int b  = mtile / kTilesPerB;
        int nn = (mtile - b * kTilesPerB) * 16 + m;
        const unsigned short* pb = poolb + (size_t)b * kNUp * kCin;

        int idxs[kSeq];
#pragma unroll
        for (int s = 0; s < kSeq; ++s) idxs[s] = indices[nn * kSeq + s];

        float bs0 = bias[m];
        float bs1 = bias[16 + m];

        __syncthreads();                             // Bs ready

        f32x4 acc0 = {0.f, 0.f, 0.f, 0.f};
        f32x4 acc1 = {0.f, 0.f, 0.f, 0.f};
#pragma unroll
        for (int s = 0; s < kSeq; ++s) {
            const short8* ar = (const short8*)(pb + (size_t)idxs[s] * kCin);
            short8 a0 = ar[kg];                      // channels 0..31
            short8 a1 = ar[4 + kg];                  // channels 32..63
            short8 b00 = Bs[(4 * s + 0) * 64 + l];
            short8 b01 = Bs[(4 * s + 1) * 64 + l];
            short8 b10 = Bs[(4 * s + 2) * 64 + l];
            short8 b11 = Bs[(4 * s + 3) * 64 + l];
            acc0 = __builtin_amdgcn_mfma_f32_16x16x32_bf16(a0, b00, acc0, 0, 0, 0);
            acc1 = __builtin_amdgcn_mfma_f32_16x16x32_bf16(a0, b01, acc1, 0, 0, 0);
            acc0 = __builtin_amdgcn_mfma_f32_16x16x32_bf16(a1, b10, acc0, 0, 0, 0);
            acc1 = __builtin_amdgcn_mfma_f32_16x16x32_bf16(a1, b11, acc1, 0, 0, 0);
        }

        int orow0 = mtile * 16 + kg * 4;
#pragma unroll
        for (int r = 0; r < 4; ++r) {
            size_t orow = (size_t)(orow0 + r) * kCout;
            __builtin_nontemporal_store(fmaxf(acc0[r] + bs0, 0.f), &out[orow + m]);
            __builtin_nontemporal_store(fmaxf(acc1[r] + bs1, 0.f), &out[orow + 16 + m]);
        }
    } else {
        __syncthreads();                             // keep barrier uniform
    }
}

extern "C" void kernel_launch(void* const* d_in, const int* in_sizes, int n_in,
                              void* d_out, int out_size, void* d_ws, size_t ws_size,
                              hipStream_t stream) {
    const float* x    = (const float*)d_in[0];
    const float* val  = (const float*)d_in[1];
    const float* W    = (const float*)d_in[2];
    const float* bias = (const float*)d_in[3];
    const int* row     = (const int*)d_in[4];
    const int* col     = (const int*)d_in[5];
    const int* indices = (const int*)d_in[6];
    float* out = (float*)d_out;

    char* wsb = (char*)d_ws;
    unsigned short* poolb = (unsigned short*)(wsb + kOffPool);
    unsigned short* wfrag = (unsigned short*)(wsb + kOffWfrag);
    int* cursor  = (int*)(wsb + kOffCur);
    uint2* bucket = (uint2*)(wsb + kOffBucket);

    zero_kernel<<<(kNUp + 255) / 256, 256, 0, stream>>>(cursor);

    constexpr int prep_blocks = kWFragN / 256 + (kE + 255) / 256;  // 72 + 331
    prep_kernel<<<prep_blocks, 256, 0, stream>>>(W, wfrag, row, col, val, cursor, bucket);

    pool_gather<<<kNUp / 16 * kB, 256, 0, stream>>>(x, cursor, bucket, poolb);

    gemm_mfma<<<kGemmGrid, 512, 0, stream>>>(poolb, wfrag, bias, indices, out);
}